// Round 4
// baseline (257.892 us; speedup 1.0000x reference)
//
#include <hip/hip_runtime.h>

// radius_graph dense mask: out[i,j] = (||pos_i-pos_j||^2 <= 9.0) ? 1 : 0 (int32)
//
// Rounding model (verified absmax=0 in round 2 — DO NOT CHANGE):
//   sq   = (x*x + y*y) + z*z                  rounded per op
//   dot  = fma(z,z', fma(y,y', x*x'))         BLAS-style FMA chain
//   d2   = (sq_i + sq_j) - 2*dot              2*dot exact; adds/sub rounded
//   mask = max(d2,0) <= 9.0f
//
// Round-3/4: AoS->SoA pre-pass into d_ws (xs/ys/zs/sq) for 16B-lane-stride
// coalesced loads (round-2 had 48B lane stride -> ~3x L1 line traffic);
// sq[j] precomputed once. Nontemporal output store via native clang vector
// (HIP int4 is a class type — rejected by __builtin_nontemporal_store).

#define NPTS 8192
#define R2 9.0f

typedef int int4v __attribute__((ext_vector_type(4)));

__global__ __launch_bounds__(256) void soa_kernel(
    const float* __restrict__ pos, float* __restrict__ xs, float* __restrict__ ys,
    float* __restrict__ zs, float* __restrict__ sq) {
    const int j = blockIdx.x * 256 + threadIdx.x;
    const float x = pos[j * 3 + 0];
    const float y = pos[j * 3 + 1];
    const float z = pos[j * 3 + 2];
    xs[j] = x;
    ys[j] = y;
    zs[j] = z;
    sq[j] = __fadd_rn(__fadd_rn(__fmul_rn(x, x), __fmul_rn(y, y)),
                      __fmul_rn(z, z));
}

__global__ __launch_bounds__(256) void radius_mask_kernel(
    const float* __restrict__ xs, const float* __restrict__ ys,
    const float* __restrict__ zs, const float* __restrict__ sq,
    int* __restrict__ out) {
    const int i = blockIdx.y;                              // row (uniform per block)
    const int j0 = (blockIdx.x * 256 + threadIdx.x) * 4;   // 4 cols per thread

    // row point: uniform -> scalar loads (sq_i from the precomputed array so
    // rounding is bit-identical to the column side)
    const float xi = xs[i];
    const float yi = ys[i];
    const float zi = zs[i];
    const float sqi = sq[i];

    // fully coalesced: 16B lane stride
    const float4 x4 = *reinterpret_cast<const float4*>(xs + j0);
    const float4 y4 = *reinterpret_cast<const float4*>(ys + j0);
    const float4 z4 = *reinterpret_cast<const float4*>(zs + j0);
    const float4 q4 = *reinterpret_cast<const float4*>(sq + j0);
    const float xj[4] = {x4.x, x4.y, x4.z, x4.w};
    const float yj[4] = {y4.x, y4.y, y4.z, y4.w};
    const float zj[4] = {z4.x, z4.y, z4.z, z4.w};
    const float qj[4] = {q4.x, q4.y, q4.z, q4.w};

    int4v res;
#pragma unroll
    for (int k = 0; k < 4; ++k) {
        const float dot = __fmaf_rn(zi, zj[k],
                           __fmaf_rn(yi, yj[k], __fmul_rn(xi, xj[k])));
        const float s = __fadd_rn(sqi, qj[k]);
        float d2 = __fsub_rn(s, __fmul_rn(2.0f, dot));
        d2 = fmaxf(d2, 0.0f);
        res[k] = (d2 <= R2) ? 1 : 0;
    }

    __builtin_nontemporal_store(
        res, reinterpret_cast<int4v*>(out) + (((size_t)i * NPTS + j0) >> 2));
}

extern "C" void kernel_launch(void* const* d_in, const int* in_sizes, int n_in,
                              void* d_out, int out_size, void* d_ws, size_t ws_size,
                              hipStream_t stream) {
    const float* pos = (const float*)d_in[0];
    int* out = (int*)d_out;

    float* xs = (float*)d_ws;          // 8192 floats each
    float* ys = xs + NPTS;
    float* zs = ys + NPTS;
    float* sq = zs + NPTS;

    soa_kernel<<<dim3(NPTS / 256), dim3(256), 0, stream>>>(pos, xs, ys, zs, sq);

    dim3 grid(NPTS / (256 * 4), NPTS, 1);
    radius_mask_kernel<<<grid, dim3(256), 0, stream>>>(xs, ys, zs, sq, out);
}